// Round 4
// baseline (579.420 us; speedup 1.0000x reference)
//
#include <hip/hip_runtime.h>
#include <hip/hip_cooperative_groups.h>
#include <stdint.h>

namespace cg = cooperative_groups;

#define FEAT 1024
#define BATCH 4096
#define SM (FEAT * FEAT)

typedef float f32x4 __attribute__((ext_vector_type(4)));
typedef short bf16x8 __attribute__((ext_vector_type(8)));
typedef unsigned short u16x8 __attribute__((ext_vector_type(8)));
typedef unsigned short u16x4 __attribute__((ext_vector_type(4)));

__device__ inline unsigned short f32_to_bf16(float f) {
  union { float f; uint32_t u; } v; v.f = f;
  uint32_t u = v.u;
  uint32_t lsb = (u >> 16) & 1u;
  u += 0x7fffu + lsb;  // RNE
  return (unsigned short)(u >> 16);
}

__device__ inline float bf16_to_f32(unsigned short h) {
  union { uint32_t u; float f; } v; v.u = (uint32_t)h << 16; return v.f;
}

__device__ inline void gload_lds16(const void* g, void* l) {
  __builtin_amdgcn_global_load_lds(
      (__attribute__((address_space(1))) void*)(g),
      (__attribute__((address_space(3))) void*)(l),
      16, 0, 0);
}

// 128x64-tile GEMM core: Y[r][C] = sum_k A[arow0+r][k0+k] * Bt[bcol0+C][k0+k]
// 4 waves (2x2), K-swizzled LDS (colbyte ^= (row&7)<<4, pre-swizzled global src).
__device__ __forceinline__ void gemm_core(
    const unsigned short* __restrict__ Ap, const unsigned short* __restrict__ Btp,
    int arow0, int bcol0, int k0, int iters, int t,
    unsigned short* As, unsigned short* Bs, f32x4 (&acc)[4][2]) {
  const int lane = t & 63;
  const int wid = t >> 6, wm = wid >> 1, wn = wid & 1;
  const int ar = t >> 3;
  const int acb = (((t & 7) ^ ((t >> 3) & 7)) << 4);
  const unsigned short* Abase = Ap + (size_t)(arow0 + ar) * FEAT + (acb >> 1) + k0;
  const unsigned short* Bbase = Btp + (size_t)(bcol0 + ar) * FEAT + (acb >> 1) + k0;
  unsigned short* AsP = As + t * 8;
  unsigned short* BsP = Bs + t * 8;
  for (int kt = 0; kt < iters; ++kt) {
    const int ko = kt * 64;
#pragma unroll
    for (int p = 0; p < 4; ++p)
      gload_lds16(Abase + (size_t)(p * 32) * FEAT + ko, AsP + p * 2048);
#pragma unroll
    for (int p = 0; p < 2; ++p)
      gload_lds16(Bbase + (size_t)(p * 32) * FEAT + ko, BsP + p * 2048);
    __syncthreads();
#pragma unroll
    for (int kk = 0; kk < 2; ++kk) {
      bf16x8 a[4], b[2];
      const int cbase = kk * 64 + ((lane >> 4) << 4);
#pragma unroll
      for (int m = 0; m < 4; ++m) {
        int r = wm * 64 + m * 16 + (lane & 15);
        a[m] = *(const bf16x8*)((const char*)As + r * 128 + (cbase ^ ((r & 7) << 4)));
      }
#pragma unroll
      for (int n = 0; n < 2; ++n) {
        int r = wn * 32 + n * 16 + (lane & 15);
        b[n] = *(const bf16x8*)((const char*)Bs + r * 128 + (cbase ^ ((r & 7) << 4)));
      }
#pragma unroll
      for (int m = 0; m < 4; ++m)
#pragma unroll
        for (int n = 0; n < 2; ++n)
          acc[m][n] = __builtin_amdgcn_mfma_f32_16x16x32_bf16(a[m], b[n], acc[m][n], 0, 0, 0);
    }
    __syncthreads();
  }
}

// One cooperative kernel for the whole pipeline. 512 blocks x 256 threads.
__global__ __launch_bounds__(256, 2) void mega(
    const float* __restrict__ M, const float* __restrict__ feat,
    const float* __restrict__ pw, const float* __restrict__ mean,
    const float* __restrict__ eps, const float* __restrict__ logvar,
    float* __restrict__ out, uint8_t* __restrict__ ws) {
  cg::grid_group grid = cg::this_grid();
  __shared__ __align__(16) unsigned char lds[24576];
  unsigned short* As = (unsigned short*)lds;            // 16 KB
  unsigned short* Bs = (unsigned short*)(lds + 16384);  // 8 KB
  auto Ts = (unsigned short(*)[68])lds;                 // 8.7 KB transpose view
  auto Tf = (float(*)[68])lds;                          // 17.4 KB f32 transpose view

  unsigned short* Dr  = (unsigned short*)(ws);                     // 16 MB
  unsigned short* Dt  = (unsigned short*)(ws + ((size_t)16 << 20));// 16 MB
  unsigned short* Xb  = (unsigned short*)(ws + ((size_t)32 << 20));//  8 MB
  unsigned short* Wb  = (unsigned short*)(ws + ((size_t)40 << 20));//  2 MB
  unsigned short* P1r = (unsigned short*)(ws + ((size_t)42 << 20));//  8 MB
  unsigned short* P1t = (unsigned short*)(ws + ((size_t)50 << 20));//  8 MB
  unsigned short* P2r = (unsigned short*)(ws + ((size_t)58 << 20));//  4 MB
  unsigned short* P2t = (unsigned short*)(ws + ((size_t)62 << 20));//  4 MB
  unsigned short* P3r = (unsigned short*)(ws + ((size_t)66 << 20));//  2 MB
  unsigned short* St  = (unsigned short*)(ws + ((size_t)68 << 20));//  2 MB
  float*          Pp  = (float*)(ws + ((size_t)70 << 20));         // 16 MB (4 x 4MB)

  const int bid = blockIdx.x;
  const int t = threadIdx.x;
  const int swz = ((bid & 7) << 6) | (bid >> 3);  // XCD-contiguous work ids (512 % 8 == 0)
  const int lane = t & 63, wid = t >> 6, wm = wid >> 1, wn = wid & 1;

  // ---- P0a: Dr[j][k][n] = bf16(c_j*M_j), Dt = transposed. 2048 tile-jobs, 4/block ----
  for (int i = 0; i < 4; ++i) {
    const int job = bid * 4 + i;
    const int j = job >> 8, rem = job & 255;
    const int n0 = (rem >> 4) * 64, k0 = (rem & 15) * 64;
    float lv = fminf(fmaxf(logvar[j], -8.f), 2.f);
    const float c = mean[j] + eps[j] * expf(0.5f * lv);
    const float* src = M + (size_t)j * SM;
    unsigned short* dr = Dr + (size_t)j * SM;
    unsigned short* dt = Dt + (size_t)j * SM;
#pragma unroll
    for (int i2 = 0; i2 < 4; ++i2) {
      int fidx = i2 * 256 + t;
      int kl = fidx >> 4, nf = fidx & 15;
      float4 v = *(const float4*)(src + (size_t)(k0 + kl) * FEAT + n0 + nf * 4);
      u16x4 o;
      o[0] = f32_to_bf16(c * v.x); o[1] = f32_to_bf16(c * v.y);
      o[2] = f32_to_bf16(c * v.z); o[3] = f32_to_bf16(c * v.w);
      *(u16x4*)&Ts[kl][nf * 4] = o;
      *(u16x4*)(dr + (size_t)(k0 + kl) * FEAT + n0 + nf * 4) = o;
    }
    __syncthreads();
#pragma unroll
    for (int i2 = 0; i2 < 2; ++i2) {
      int cidx = t * 2 + i2;
      int nl = cidx >> 3, kc = (cidx & 7) * 8;
      u16x8 o;
#pragma unroll
      for (int r = 0; r < 8; ++r) o[r] = Ts[kc + r][nl];
      *(u16x8*)(dt + (size_t)(n0 + nl) * FEAT + k0 + kc) = o;
    }
    __syncthreads();
  }
  // ---- P0b: Xb = bf16(features), Wb = bf16(proj_w) ----
  for (int i = bid * 256 + t; i < 655360; i += 131072) {
    const float* in; unsigned short* o8; int ci;
    if (i < 524288) { in = feat; o8 = Xb; ci = i; }
    else            { in = pw;   o8 = Wb; ci = i - 524288; }
    const float4* p = (const float4*)in + (size_t)ci * 2;
    float4 a = p[0], b = p[1];
    u16x8 o;
    o[0] = f32_to_bf16(a.x); o[1] = f32_to_bf16(a.y);
    o[2] = f32_to_bf16(a.z); o[3] = f32_to_bf16(a.w);
    o[4] = f32_to_bf16(b.x); o[5] = f32_to_bf16(b.y);
    o[6] = f32_to_bf16(b.z); o[7] = f32_to_bf16(b.w);
    *((u16x8*)o8 + ci) = o;
  }
  grid.sync();

  // ---- P1: L1 pair-composes: P1[z] = D2z + D2z+1 + D2z@D2z+1 (4 slices, full-K) ----
  {
    const int z = swz >> 7, rem = swz & 127;
    const int bm = rem >> 4, bn = rem & 15;
    f32x4 acc[4][2];
#pragma unroll
    for (int m = 0; m < 4; ++m)
#pragma unroll
      for (int n = 0; n < 2; ++n) acc[m][n] = (f32x4)0.f;
    gemm_core(Dr + (size_t)(2 * z) * SM, Dt + (size_t)(2 * z + 1) * SM,
              bm * 128, bn * 64, 0, 16, t, As, Bs, acc);
    const unsigned short* aA = Dr + (size_t)(2 * z) * SM;
    const unsigned short* aB = Dr + (size_t)(2 * z + 1) * SM;
    unsigned short* pr = P1r + (size_t)z * SM;
    unsigned short* pt = P1t + (size_t)z * SM;
#pragma unroll
    for (int m = 0; m < 4; ++m) {
      int Rb = bm * 128 + wm * 64 + m * 16 + ((lane >> 4) << 2);
#pragma unroll
      for (int n = 0; n < 2; ++n) {
        int C = bn * 64 + wn * 32 + n * 16 + (lane & 15);
        u16x4 tp;
#pragma unroll
        for (int r2 = 0; r2 < 4; ++r2) {
          size_t idx = (size_t)(Rb + r2) * FEAT + C;
          float v = acc[m][n][r2] + bf16_to_f32(aA[idx]) + bf16_to_f32(aB[idx]);
          unsigned short h = f32_to_bf16(v);
          pr[idx] = h; tp[r2] = h;
        }
        *(u16x4*)(pt + (size_t)C * FEAT + Rb) = tp;
      }
    }
  }
  grid.sync();

  // ---- P2: L2 quad-composes, split-K2 (2 slices x 128 tiles x 2 ksplits) ----
  {
    const int z = swz >> 8, rem2 = swz & 255;
    const int ks = rem2 >> 7, tile = rem2 & 127;
    const int bm = tile >> 4, bn = tile & 15;
    f32x4 acc[4][2];
#pragma unroll
    for (int m = 0; m < 4; ++m)
#pragma unroll
      for (int n = 0; n < 2; ++n) acc[m][n] = (f32x4)0.f;
    gemm_core(P1r + (size_t)(2 * z) * SM, P1t + (size_t)(2 * z + 1) * SM,
              bm * 128, bn * 64, ks * 512, 8, t, As, Bs, acc);
    float* pp = Pp + (size_t)(z * 2 + ks) * SM;
#pragma unroll
    for (int m = 0; m < 4; ++m) {
      int Rb = bm * 128 + wm * 64 + m * 16 + ((lane >> 4) << 2);
#pragma unroll
      for (int n = 0; n < 2; ++n) {
        int C = bn * 64 + wn * 32 + n * 16 + (lane & 15);
#pragma unroll
        for (int r2 = 0; r2 < 4; ++r2)
          pp[(size_t)(Rb + r2) * FEAT + C] = acc[m][n][r2];
      }
    }
  }
  grid.sync();

  // ---- P2r: reduce partials + linear terms -> P2r (rows) + P2t (transposed) ----
  {
    const int z = bid >> 8, rem = bid & 255;
    const int k0 = (rem >> 4) * 64, n0 = (rem & 15) * 64;
    const float* p0 = Pp + (size_t)(2 * z) * SM;
    const float* p1 = Pp + (size_t)(2 * z + 1) * SM;
    const unsigned short* a0 = P1r + (size_t)(2 * z) * SM;
    const unsigned short* a1 = P1r + (size_t)(2 * z + 1) * SM;
    unsigned short* pr = P2r + (size_t)z * SM;
    unsigned short* pt = P2t + (size_t)z * SM;
#pragma unroll
    for (int i2 = 0; i2 < 4; ++i2) {
      int fidx = i2 * 256 + t;
      int kl = fidx >> 4, nf = fidx & 15;
      size_t idx = (size_t)(k0 + kl) * FEAT + n0 + nf * 4;
      float4 v0 = *(const float4*)(p0 + idx);
      float4 v1 = *(const float4*)(p1 + idx);
      u16x4 q0 = *(const u16x4*)(a0 + idx);
      u16x4 q1 = *(const u16x4*)(a1 + idx);
      u16x4 o;
      o[0] = f32_to_bf16(v0.x + v1.x + bf16_to_f32(q0[0]) + bf16_to_f32(q1[0]));
      o[1] = f32_to_bf16(v0.y + v1.y + bf16_to_f32(q0[1]) + bf16_to_f32(q1[1]));
      o[2] = f32_to_bf16(v0.z + v1.z + bf16_to_f32(q0[2]) + bf16_to_f32(q1[2]));
      o[3] = f32_to_bf16(v0.w + v1.w + bf16_to_f32(q0[3]) + bf16_to_f32(q1[3]));
      *(u16x4*)&Ts[kl][nf * 4] = o;
      *(u16x4*)(pr + idx) = o;
    }
    __syncthreads();
#pragma unroll
    for (int i2 = 0; i2 < 2; ++i2) {
      int cidx = t * 2 + i2;
      int nl = cidx >> 3, kc = (cidx & 7) * 8;
      u16x8 o;
#pragma unroll
      for (int r = 0; r < 8; ++r) o[r] = Ts[kc + r][nl];
      *(u16x8*)(pt + (size_t)(n0 + nl) * FEAT + k0 + kc) = o;
    }
    __syncthreads();
  }
  grid.sync();

  // ---- P3: L3 oct-compose, split-K4 (128 tiles x 4 ksplits) ----
  {
    const int ks = swz & 3, tile = swz >> 2;
    const int bm = tile >> 4, bn = tile & 15;
    f32x4 acc[4][2];
#pragma unroll
    for (int m = 0; m < 4; ++m)
#pragma unroll
      for (int n = 0; n < 2; ++n) acc[m][n] = (f32x4)0.f;
    gemm_core(P2r, P2t + SM, bm * 128, bn * 64, ks * 256, 4, t, As, Bs, acc);
    float* pp = Pp + (size_t)ks * SM;
#pragma unroll
    for (int m = 0; m < 4; ++m) {
      int Rb = bm * 128 + wm * 64 + m * 16 + ((lane >> 4) << 2);
#pragma unroll
      for (int n = 0; n < 2; ++n) {
        int C = bn * 64 + wn * 32 + n * 16 + (lane & 15);
#pragma unroll
        for (int r2 = 0; r2 < 4; ++r2)
          pp[(size_t)(Rb + r2) * FEAT + C] = acc[m][n][r2];
      }
    }
  }
  grid.sync();

  // ---- P3r: reduce -> P3r (row-major bf16 only) ----
  for (int i = bid * 256 + t; i < 262144; i += 131072) {
    size_t idx = (size_t)i * 4;
    float4 v0 = *(const float4*)(Pp + idx);
    float4 v1 = *(const float4*)(Pp + SM + idx);
    float4 v2 = *(const float4*)(Pp + 2 * SM + idx);
    float4 v3 = *(const float4*)(Pp + 3 * SM + idx);
    u16x4 q0 = *(const u16x4*)(P2r + idx);
    u16x4 q1 = *(const u16x4*)(P2r + SM + idx);
    u16x4 o;
    o[0] = f32_to_bf16(v0.x + v1.x + v2.x + v3.x + bf16_to_f32(q0[0]) + bf16_to_f32(q1[0]));
    o[1] = f32_to_bf16(v0.y + v1.y + v2.y + v3.y + bf16_to_f32(q0[1]) + bf16_to_f32(q1[1]));
    o[2] = f32_to_bf16(v0.z + v1.z + v2.z + v3.z + bf16_to_f32(q0[2]) + bf16_to_f32(q1[2]));
    o[3] = f32_to_bf16(v0.w + v1.w + v2.w + v3.w + bf16_to_f32(q0[3]) + bf16_to_f32(q1[3]));
    *(u16x4*)(P3r + idx) = o;
  }
  grid.sync();

  // ---- P4: L4 S-build GEMM part: Y = P3 @ W^T, split-K4 ----
  {
    const int ks = swz & 3, tile = swz >> 2;
    const int bm = tile >> 4, bn = tile & 15;
    f32x4 acc[4][2];
#pragma unroll
    for (int m = 0; m < 4; ++m)
#pragma unroll
      for (int n = 0; n < 2; ++n) acc[m][n] = (f32x4)0.f;
    gemm_core(P3r, Wb, bm * 128, bn * 64, ks * 256, 4, t, As, Bs, acc);
    float* pp = Pp + (size_t)ks * SM;
#pragma unroll
    for (int m = 0; m < 4; ++m) {
      int Rb = bm * 128 + wm * 64 + m * 16 + ((lane >> 4) << 2);
#pragma unroll
      for (int n = 0; n < 2; ++n) {
        int C = bn * 64 + wn * 32 + n * 16 + (lane & 15);
#pragma unroll
        for (int r2 = 0; r2 < 4; ++r2)
          pp[(size_t)(Rb + r2) * FEAT + C] = acc[m][n][r2];
      }
    }
  }
  grid.sync();

  // ---- P4r: St[n][k] = bf16(sum partials[k][n] + W[n][k])  (256 tile jobs) ----
  if (bid < 256) {
    const int k0 = (bid >> 4) * 64, n0 = (bid & 15) * 64;
#pragma unroll
    for (int i2 = 0; i2 < 4; ++i2) {
      int fidx = i2 * 256 + t;
      int kl = fidx >> 4, nf = fidx & 15;
      size_t idx = (size_t)(k0 + kl) * FEAT + n0 + nf * 4;
      float4 v0 = *(const float4*)(Pp + idx);
      float4 v1 = *(const float4*)(Pp + SM + idx);
      float4 v2 = *(const float4*)(Pp + 2 * SM + idx);
      float4 v3 = *(const float4*)(Pp + 3 * SM + idx);
      float4 s;
      s.x = v0.x + v1.x + v2.x + v3.x;
      s.y = v0.y + v1.y + v2.y + v3.y;
      s.z = v0.z + v1.z + v2.z + v3.z;
      s.w = v0.w + v1.w + v2.w + v3.w;
      *(float4*)&Tf[kl][nf * 4] = s;
    }
    __syncthreads();
#pragma unroll
    for (int i2 = 0; i2 < 2; ++i2) {
      int cidx = t * 2 + i2;
      int nl = cidx >> 3, kc = (cidx & 7) * 8;
      u16x8 o;
#pragma unroll
      for (int r = 0; r < 8; ++r) {
        float v = Tf[kc + r][nl] + bf16_to_f32(Wb[(size_t)(n0 + nl) * FEAT + k0 + kc + r]);
        o[r] = f32_to_bf16(v);
      }
      *(u16x8*)(St + (size_t)(n0 + nl) * FEAT + k0 + kc) = o;
    }
  }
  grid.sync();

  // ---- P5: out = Xb @ S (32 x 16 tiles, f32 out) ----
  {
    const int bm = swz >> 4, bn = swz & 15;
    f32x4 acc[4][2];
#pragma unroll
    for (int m = 0; m < 4; ++m)
#pragma unroll
      for (int n = 0; n < 2; ++n) acc[m][n] = (f32x4)0.f;
    gemm_core(Xb, St, bm * 128, bn * 64, 0, 16, t, As, Bs, acc);
#pragma unroll
    for (int m = 0; m < 4; ++m) {
      int Rb = bm * 128 + wm * 64 + m * 16 + ((lane >> 4) << 2);
#pragma unroll
      for (int n = 0; n < 2; ++n) {
        int C = bn * 64 + wn * 32 + n * 16 + (lane & 15);
#pragma unroll
        for (int r2 = 0; r2 < 4; ++r2)
          out[(size_t)(Rb + r2) * FEAT + C] = acc[m][n][r2];
      }
    }
  }
}

extern "C" void kernel_launch(void* const* d_in, const int* in_sizes, int n_in,
                              void* d_out, int out_size, void* d_ws, size_t ws_size,
                              hipStream_t stream) {
  const float* features = (const float*)d_in[0];
  const float* eps      = (const float*)d_in[1];
  const float* mean     = (const float*)d_in[2];
  const float* logvar   = (const float*)d_in[3];
  const float* task_mats= (const float*)d_in[4];
  const float* proj_w   = (const float*)d_in[5];
  float* out = (float*)d_out;
  uint8_t* ws = (uint8_t*)d_ws;

  void* args[8] = {
      (void*)&task_mats, (void*)&features, (void*)&proj_w,
      (void*)&mean, (void*)&eps, (void*)&logvar,
      (void*)&out, (void*)&ws};
  hipLaunchCooperativeKernel((const void*)mega, dim3(512), dim3(256), args, 0, stream);
}

// Round 5
// 87.265 us; speedup vs baseline: 6.6398x; 6.6398x over previous
//
#include <hip/hip_runtime.h>
#include <stdint.h>

#define FEAT 1024
#define BATCH 4096
#define SM (FEAT * FEAT)

typedef float f32x4 __attribute__((ext_vector_type(4)));
typedef short bf16x8 __attribute__((ext_vector_type(8)));
typedef unsigned short u16x8 __attribute__((ext_vector_type(8)));
typedef unsigned short u16x4 __attribute__((ext_vector_type(4)));

__device__ inline unsigned short f32_to_bf16(float f) {
  union { float f; uint32_t u; } v; v.f = f;
  uint32_t u = v.u;
  uint32_t lsb = (u >> 16) & 1u;
  u += 0x7fffu + lsb;  // RNE
  return (unsigned short)(u >> 16);
}

__device__ inline float bf16_to_f32(unsigned short h) {
  union { uint32_t u; float f; } v; v.u = (uint32_t)h << 16; return v.f;
}

__device__ inline void gload_lds16(const void* g, void* l) {
  __builtin_amdgcn_global_load_lds(
      (__attribute__((address_space(1))) void*)(g),
      (__attribute__((address_space(3))) void*)(l),
      16, 0, 0);
}

// ---- fused prep: Dr[j]=bf16(c_j*M_j) (all j), Dt[j>>1]=transposed (odd j only),
// ---- Xb=bf16(features), Wb=bf16(proj_w). 2304 blocks.
__global__ void conv_all(const float* __restrict__ M, const float* __restrict__ feat,
                         const float* __restrict__ pw, const float* __restrict__ mean,
                         const float* __restrict__ eps, const float* __restrict__ logvar,
                         unsigned short* __restrict__ Dr, unsigned short* __restrict__ Dt,
                         unsigned short* __restrict__ Xb, unsigned short* __restrict__ Wb) {
  const int bid = blockIdx.x;
  const int t = threadIdx.x;
  if (bid < 2048) {
    __shared__ unsigned short Ts[64][68];
    const int j = bid >> 8, rem = bid & 255;
    const int n0 = (rem >> 4) * 64, k0 = (rem & 15) * 64;
    float lv = fminf(fmaxf(logvar[j], -8.f), 2.f);
    const float c = mean[j] + eps[j] * expf(0.5f * lv);
    const float* src = M + (size_t)j * SM;
    unsigned short* dr = Dr + (size_t)j * SM;
#pragma unroll
    for (int i2 = 0; i2 < 4; ++i2) {
      int fidx = i2 * 256 + t;
      int kl = fidx >> 4, nf = fidx & 15;
      float4 v = *(const float4*)(src + (size_t)(k0 + kl) * FEAT + n0 + nf * 4);
      u16x4 o;
      o[0] = f32_to_bf16(c * v.x); o[1] = f32_to_bf16(c * v.y);
      o[2] = f32_to_bf16(c * v.z); o[3] = f32_to_bf16(c * v.w);
      *(u16x4*)&Ts[kl][nf * 4] = o;
      *(u16x4*)(dr + (size_t)(k0 + kl) * FEAT + n0 + nf * 4) = o;
    }
    __syncthreads();
    if (j & 1) {
      unsigned short* dt = Dt + (size_t)(j >> 1) * SM;
#pragma unroll
      for (int i2 = 0; i2 < 2; ++i2) {
        int cidx = t * 2 + i2;
        int nl = cidx >> 3, kc = (cidx & 7) * 8;
        u16x8 o;
#pragma unroll
        for (int r = 0; r < 8; ++r) o[r] = Ts[kc + r][nl];
        *(u16x8*)(dt + (size_t)(n0 + nl) * FEAT + k0 + kc) = o;
      }
    }
  } else {
    for (int i = (bid - 2048) * 256 + t; i < 655360; i += 65536) {
      const float* in; unsigned short* o8; int ci;
      if (i < 524288) { in = feat; o8 = Xb; ci = i; }
      else            { in = pw;   o8 = Wb; ci = i - 524288; }
      const float4* p = (const float4*)in + (size_t)ci * 2;
      float4 a = p[0], b = p[1];
      u16x8 o;
      o[0] = f32_to_bf16(a.x); o[1] = f32_to_bf16(a.y);
      o[2] = f32_to_bf16(a.z); o[3] = f32_to_bf16(a.w);
      o[4] = f32_to_bf16(b.x); o[5] = f32_to_bf16(b.y);
      o[6] = f32_to_bf16(b.z); o[7] = f32_to_bf16(b.w);
      *((u16x8*)o8 + ci) = o;
    }
  }
}

// ---- 2-phase double-buffered GEMM core: Y[r][C] = sum_k A[arow0+r][k]*Bt[bcol0+C][k]
// K=1024 (16 steps of 64). LDS: As = 2 x 8192 elems, Bs = 2 x 4096 elems (48 KB).
// XOR-swizzled (colbyte ^= (row&7)<<4), pre-swizzled global source.
// One __syncthreads per K-step; next tile's global_load_lds issued BEFORE compute.
__device__ __forceinline__ void gemm_core(
    const unsigned short* __restrict__ Ap, const unsigned short* __restrict__ Btp,
    int arow0, int bcol0, int t,
    unsigned short* As, unsigned short* Bs, f32x4 (&acc)[4][2]) {
  const int lane = t & 63;
  const int wid = t >> 6, wm = wid >> 1, wn = wid & 1;
  const int ar = t >> 3;
  const int acb = (((t & 7) ^ ((t >> 3) & 7)) << 4);
  const unsigned short* Abase = Ap + (size_t)(arow0 + ar) * FEAT + (acb >> 1);
  const unsigned short* Bbase = Btp + (size_t)(bcol0 + ar) * FEAT + (acb >> 1);
  unsigned short* AsP = As + t * 8;
  unsigned short* BsP = Bs + t * 8;

  // prologue: stage K-tile 0 into buffer 0
#pragma unroll
  for (int p = 0; p < 4; ++p) gload_lds16(Abase + (size_t)(p * 32) * FEAT, AsP + p * 2048);
#pragma unroll
  for (int p = 0; p < 2; ++p) gload_lds16(Bbase + (size_t)(p * 32) * FEAT, BsP + p * 2048);
  __syncthreads();

  for (int kt = 0; kt < 16; ++kt) {
    const int cur = kt & 1, nb = cur ^ 1;
    // prefetch next K-tile into the other buffer (overlaps with compute below)
    if (kt < 15) {
      const int ko = (kt + 1) * 64;
#pragma unroll
      for (int p = 0; p < 4; ++p)
        gload_lds16(Abase + (size_t)(p * 32) * FEAT + ko, AsP + nb * 8192 + p * 2048);
#pragma unroll
      for (int p = 0; p < 2; ++p)
        gload_lds16(Bbase + (size_t)(p * 32) * FEAT + ko, BsP + nb * 4096 + p * 2048);
    }
    const char* Asc = (const char*)(As + cur * 8192);
    const char* Bsc = (const char*)(Bs + cur * 4096);
#pragma unroll
    for (int kk = 0; kk < 2; ++kk) {
      bf16x8 a[4], b[2];
      const int cbase = kk * 64 + ((lane >> 4) << 4);
#pragma unroll
      for (int m = 0; m < 4; ++m) {
        int r = wm * 64 + m * 16 + (lane & 15);
        a[m] = *(const bf16x8*)(Asc + r * 128 + (cbase ^ ((r & 7) << 4)));
      }
#pragma unroll
      for (int n = 0; n < 2; ++n) {
        int r = wn * 32 + n * 16 + (lane & 15);
        b[n] = *(const bf16x8*)(Bsc + r * 128 + (cbase ^ ((r & 7) << 4)));
      }
#pragma unroll
      for (int m = 0; m < 4; ++m)
#pragma unroll
        for (int n = 0; n < 2; ++n)
          acc[m][n] = __builtin_amdgcn_mfma_f32_16x16x32_bf16(a[m], b[n], acc[m][n], 0, 0, 0);
    }
    __syncthreads();  // drains vmcnt (prefetch) + readies buffer swap
  }
}

// MODE 0 (L1, 512 blk): z=swz>>7; P1[z] = D2z + D2z+1 + D2z@D2z+1.
//   A=Dr+2z*SM, Bt=Dt+z*SM (odd-packed), aB=Dr+(2z+1)*SM. Write Pr+z*SM always,
//   Pt+(z>>1)*SM if z odd (transposed).
// MODE 1 (L2, 256 blk): z=swz>>7; P2[z] = P1_2z + P1_2z+1 + P1_2z@P1_2z+1.
//   A=P1r+2z*SM, Bt=P1t+z*SM (odd-packed), aB=P1r+(2z+1)*SM. Write Pt+z*SM ONLY.
// MODE 2 (B-step, 512 blk): Xd = bf16(A + A@Delta). Bt = P2t slice (direct ptr).
// MODE 3 (B3, 512 blk): outf = A @ W^T (Bt = Wb row-major).
template <int MODE>
__global__ __launch_bounds__(256, 2) void gemm_tree(
    const unsigned short* __restrict__ A, const unsigned short* __restrict__ Bt,
    const unsigned short* __restrict__ aBb,
    unsigned short* __restrict__ Pr, unsigned short* __restrict__ Pt,
    unsigned short* __restrict__ Xd, float* __restrict__ outf) {
  __shared__ __align__(16) unsigned short lds[24576];  // 48 KB
  unsigned short* As = lds;
  unsigned short* Bs = lds + 16384;

  const int t = threadIdx.x;
  const int lane = t & 63, wid = t >> 6, wm = wid >> 1, wn = wid & 1;
  const int nb = (int)gridDim.x;
  const int swz = (blockIdx.x & 7) * (nb >> 3) + (blockIdx.x >> 3);  // XCD-bijective

  int bm, bn, z = 0;
  const unsigned short *Ap, *Btp, *aA = nullptr, *aB = nullptr;
  if (MODE <= 1) {
    z = swz >> 7;
    const int rem = swz & 127;
    bm = rem >> 4; bn = rem & 15;
    Ap = A + (size_t)(2 * z) * SM;
    Btp = Bt + (size_t)z * SM;
    aA = Ap;
    aB = aBb + (size_t)(2 * z + 1) * SM;
  } else {
    bm = swz >> 4; bn = swz & 15;
    Ap = A; Btp = Bt;
  }

  f32x4 acc[4][2];
#pragma unroll
  for (int m = 0; m < 4; ++m)
#pragma unroll
    for (int n = 0; n < 2; ++n) acc[m][n] = (f32x4)0.f;

  gemm_core(Ap, Btp, bm * 128, bn * 64, t, As, Bs, acc);

  // epilogue. C/D layout: col = lane&15, row = (lane>>4)*4 + reg [HW-verified]
#pragma unroll
  for (int m = 0; m < 4; ++m) {
    int Rb = bm * 128 + wm * 64 + m * 16 + ((lane >> 4) << 2);
#pragma unroll
    for (int n = 0; n < 2; ++n) {
      int C = bn * 64 + wn * 32 + n * 16 + (lane & 15);
      if (MODE == 0) {
        unsigned short* pr = Pr + (size_t)z * SM;
        u16x4 tp;
#pragma unroll
        for (int r2 = 0; r2 < 4; ++r2) {
          size_t idx = (size_t)(Rb + r2) * FEAT + C;
          float v = acc[m][n][r2] + bf16_to_f32(aA[idx]) + bf16_to_f32(aB[idx]);
          unsigned short h = f32_to_bf16(v);
          pr[idx] = h; tp[r2] = h;
        }
        if (z & 1)
          *(u16x4*)(Pt + (size_t)(z >> 1) * SM + (size_t)C * FEAT + Rb) = tp;
      } else if (MODE == 1) {
        u16x4 tp;
#pragma unroll
        for (int r2 = 0; r2 < 4; ++r2) {
          size_t idx = (size_t)(Rb + r2) * FEAT + C;
          float v = acc[m][n][r2] + bf16_to_f32(aA[idx]) + bf16_to_f32(aB[idx]);
          tp[r2] = f32_to_bf16(v);
        }
        *(u16x4*)(Pt + (size_t)z * SM + (size_t)C * FEAT + Rb) = tp;
      } else if (MODE == 2) {
#pragma unroll
        for (int r2 = 0; r2 < 4; ++r2) {
          size_t idx = (size_t)(Rb + r2) * FEAT + C;
          float v = acc[m][n][r2] + bf16_to_f32(A[idx]);  // residual = A itself
          Xd[idx] = f32_to_bf16(v);
        }
      } else {
#pragma unroll
        for (int r2 = 0; r2 < 4; ++r2)
          outf[(size_t)(Rb + r2) * FEAT + C] = acc[m][n][r2];
      }
    }
  }
}

extern "C" void kernel_launch(void* const* d_in, const int* in_sizes, int n_in,
                              void* d_out, int out_size, void* d_ws, size_t ws_size,
                              hipStream_t stream) {
  const float* features = (const float*)d_in[0];
  const float* eps      = (const float*)d_in[1];
  const float* mean     = (const float*)d_in[2];
  const float* logvar   = (const float*)d_in[3];
  const float* task_mats= (const float*)d_in[4];
  const float* proj_w   = (const float*)d_in[5];
  float* out = (float*)d_out;

  // workspace (peak 50 MB, launch-ordered lifetimes):
  uint8_t* ws = (uint8_t*)d_ws;
  unsigned short* Dr  = (unsigned short*)(ws);                      //  0..16M (dead after L2)
  unsigned short* Dt  = (unsigned short*)(ws + ((size_t)16 << 20)); // 16..24M odd-packed (dead after L1)
  unsigned short* Xb  = (unsigned short*)(ws + ((size_t)24 << 20)); // 24..32M (dead after B1)
  unsigned short* Wb  = (unsigned short*)(ws + ((size_t)32 << 20)); // 32..34M (live to B3)
  unsigned short* P1r = (unsigned short*)(ws + ((size_t)34 << 20)); // 34..42M (dead after L2)
  unsigned short* P1t = (unsigned short*)(ws + ((size_t)42 << 20)); // 42..46M odd-packed (dead after L2)
  unsigned short* P2t = (unsigned short*)(ws + ((size_t)46 << 20)); // 46..50M (dead after B2)
  unsigned short* X1  = (unsigned short*)(ws + ((size_t)16 << 20)); // over dead Dt
  unsigned short* X2  = (unsigned short*)(ws + ((size_t)34 << 20)); // over dead P1r

  // prep: deltas + bf16 converts (one launch)
  conv_all<<<2304, 256, 0, stream>>>(task_mats, features, proj_w, mean, eps, logvar,
                                     Dr, Dt, Xb, Wb);
  // L1: P1[z] = D2z + D2z+1 + D2z@D2z+1  (4 slices, 512 blocks)
  gemm_tree<0><<<512, 256, 0, stream>>>(Dr, Dt, Dr, P1r, P1t, nullptr, nullptr);
  // L2: P2[z] = P1_2z + P1_2z+1 + P1_2z@P1_2z+1, transposed-only out (256 blocks)
  gemm_tree<1><<<256, 256, 0, stream>>>(P1r, P1t, P1r, nullptr, P2t, nullptr, nullptr);
  // B1: x1 = x + x@DeltaL
  gemm_tree<2><<<512, 256, 0, stream>>>(Xb, P2t, nullptr, nullptr, nullptr, X1, nullptr);
  // B2: x2 = x1 + x1@DeltaR
  gemm_tree<2><<<512, 256, 0, stream>>>(X1, P2t + SM, nullptr, nullptr, nullptr, X2, nullptr);
  // B3: out = x2 @ W^T
  gemm_tree<3><<<512, 256, 0, stream>>>(X2, Wb, nullptr, nullptr, nullptr, nullptr, out);
}

// Round 6
// 84.615 us; speedup vs baseline: 6.8477x; 1.0313x over previous
//
#include <hip/hip_runtime.h>
#include <stdint.h>

#define FEAT 1024
#define BATCH 4096
#define SM (FEAT * FEAT)

typedef float f32x4 __attribute__((ext_vector_type(4)));
typedef short bf16x8 __attribute__((ext_vector_type(8)));
typedef unsigned short u16x8 __attribute__((ext_vector_type(8)));
typedef unsigned short u16x4 __attribute__((ext_vector_type(4)));

__device__ inline unsigned short f32_to_bf16(float f) {
  union { float f; uint32_t u; } v; v.f = f;
  uint32_t u = v.u;
  uint32_t lsb = (u >> 16) & 1u;
  u += 0x7fffu + lsb;  // RNE
  return (unsigned short)(u >> 16);
}

__device__ inline float bf16_to_f32(unsigned short h) {
  union { uint32_t u; float f; } v; v.u = (uint32_t)h << 16; return v.f;
}

__device__ inline void gload_lds16(const void* g, void* l) {
  __builtin_amdgcn_global_load_lds(
      (__attribute__((address_space(1))) void*)(g),
      (__attribute__((address_space(3))) void*)(l),
      16, 0, 0);
}

// ---- fused prep: Dr[j]=bf16(c_j*M_j) (all j), Dt[j>>1]=transposed (odd j only),
// ---- Xb=bf16(features), Wb=bf16(proj_w). 2304 blocks.
__global__ void conv_all(const float* __restrict__ M, const float* __restrict__ feat,
                         const float* __restrict__ pw, const float* __restrict__ mean,
                         const float* __restrict__ eps, const float* __restrict__ logvar,
                         unsigned short* __restrict__ Dr, unsigned short* __restrict__ Dt,
                         unsigned short* __restrict__ Xb, unsigned short* __restrict__ Wb) {
  const int bid = blockIdx.x;
  const int t = threadIdx.x;
  if (bid < 2048) {
    __shared__ unsigned short Ts[64][68];
    const int j = bid >> 8, rem = bid & 255;
    const int n0 = (rem >> 4) * 64, k0 = (rem & 15) * 64;
    float lv = fminf(fmaxf(logvar[j], -8.f), 2.f);
    const float c = mean[j] + eps[j] * expf(0.5f * lv);
    const float* src = M + (size_t)j * SM;
    unsigned short* dr = Dr + (size_t)j * SM;
#pragma unroll
    for (int i2 = 0; i2 < 4; ++i2) {
      int fidx = i2 * 256 + t;
      int kl = fidx >> 4, nf = fidx & 15;
      float4 v = *(const float4*)(src + (size_t)(k0 + kl) * FEAT + n0 + nf * 4);
      u16x4 o;
      o[0] = f32_to_bf16(c * v.x); o[1] = f32_to_bf16(c * v.y);
      o[2] = f32_to_bf16(c * v.z); o[3] = f32_to_bf16(c * v.w);
      *(u16x4*)&Ts[kl][nf * 4] = o;
      *(u16x4*)(dr + (size_t)(k0 + kl) * FEAT + n0 + nf * 4) = o;
    }
    __syncthreads();
    if (j & 1) {
      unsigned short* dt = Dt + (size_t)(j >> 1) * SM;
#pragma unroll
      for (int i2 = 0; i2 < 2; ++i2) {
        int cidx = t * 2 + i2;
        int nl = cidx >> 3, kc = (cidx & 7) * 8;
        u16x8 o;
#pragma unroll
        for (int r = 0; r < 8; ++r) o[r] = Ts[kc + r][nl];
        *(u16x8*)(dt + (size_t)(n0 + nl) * FEAT + k0 + kc) = o;
      }
    }
  } else {
    for (int i = (bid - 2048) * 256 + t; i < 655360; i += 65536) {
      const float* in; unsigned short* o8; int ci;
      if (i < 524288) { in = feat; o8 = Xb; ci = i; }
      else            { in = pw;   o8 = Wb; ci = i - 524288; }
      const float4* p = (const float4*)in + (size_t)ci * 2;
      float4 a = p[0], b = p[1];
      u16x8 o;
      o[0] = f32_to_bf16(a.x); o[1] = f32_to_bf16(a.y);
      o[2] = f32_to_bf16(a.z); o[3] = f32_to_bf16(a.w);
      o[4] = f32_to_bf16(b.x); o[5] = f32_to_bf16(b.y);
      o[6] = f32_to_bf16(b.z); o[7] = f32_to_bf16(b.w);
      *((u16x8*)o8 + ci) = o;
    }
  }
}

// ---- 2-phase double-buffered GEMM core (ITERS K-steps of 64 starting at k0) ----
// LDS: As = 2 x 8192 elems, Bs = 2 x 4096 elems (48 KB total).
// XOR-swizzled (colbyte ^= (row&7)<<4), pre-swizzled global source.
template <int ITERS>
__device__ __forceinline__ void gemm_core(
    const unsigned short* __restrict__ Ap, const unsigned short* __restrict__ Btp,
    int arow0, int bcol0, int k0, int t,
    unsigned short* As, unsigned short* Bs, f32x4 (&acc)[4][2]) {
  const int lane = t & 63;
  const int wid = t >> 6, wm = wid >> 1, wn = wid & 1;
  const int ar = t >> 3;
  const int acb = (((t & 7) ^ ((t >> 3) & 7)) << 4);
  const unsigned short* Abase = Ap + (size_t)(arow0 + ar) * FEAT + (acb >> 1) + k0;
  const unsigned short* Bbase = Btp + (size_t)(bcol0 + ar) * FEAT + (acb >> 1) + k0;
  unsigned short* AsP = As + t * 8;
  unsigned short* BsP = Bs + t * 8;

#pragma unroll
  for (int p = 0; p < 4; ++p) gload_lds16(Abase + (size_t)(p * 32) * FEAT, AsP + p * 2048);
#pragma unroll
  for (int p = 0; p < 2; ++p) gload_lds16(Bbase + (size_t)(p * 32) * FEAT, BsP + p * 2048);
  __syncthreads();

  for (int kt = 0; kt < ITERS; ++kt) {
    const int cur = kt & 1, nb = cur ^ 1;
    if (kt < ITERS - 1) {
      const int ko = (kt + 1) * 64;
#pragma unroll
      for (int p = 0; p < 4; ++p)
        gload_lds16(Abase + (size_t)(p * 32) * FEAT + ko, AsP + nb * 8192 + p * 2048);
#pragma unroll
      for (int p = 0; p < 2; ++p)
        gload_lds16(Bbase + (size_t)(p * 32) * FEAT + ko, BsP + nb * 4096 + p * 2048);
    }
    const char* Asc = (const char*)(As + cur * 8192);
    const char* Bsc = (const char*)(Bs + cur * 4096);
#pragma unroll
    for (int kk = 0; kk < 2; ++kk) {
      bf16x8 a[4], b[2];
      const int cbase = kk * 64 + ((lane >> 4) << 4);
#pragma unroll
      for (int m = 0; m < 4; ++m) {
        int r = wm * 64 + m * 16 + (lane & 15);
        a[m] = *(const bf16x8*)(Asc + r * 128 + (cbase ^ ((r & 7) << 4)));
      }
#pragma unroll
      for (int n = 0; n < 2; ++n) {
        int r = wn * 32 + n * 16 + (lane & 15);
        b[n] = *(const bf16x8*)(Bsc + r * 128 + (cbase ^ ((r & 7) << 4)));
      }
#pragma unroll
      for (int m = 0; m < 4; ++m)
#pragma unroll
        for (int n = 0; n < 2; ++n)
          acc[m][n] = __builtin_amdgcn_mfma_f32_16x16x32_bf16(a[m], b[n], acc[m][n], 0, 0, 0);
    }
    __syncthreads();
  }
}

// MODE 0 (L1, 512): z=swz>>7; P1[z] = D2z + D2z+1 + D2z@D2z+1 -> O1+z*SM rows,
//        O2+(z>>1)*SM transposed if z odd.  lin = Dr.
// MODE 1 (L2sk, 512): z=swz>>8, ks=(swz>>7)&1; partial(A_{2z} @ Bt_z, K-half ks)
//        -> O1+(2z+ks)*SM (bf16, no linear).
// MODE 2/3 (L3sk/L4sk, 512): ks=swz>>7; partial over K-quarter ks -> O1+ks*SM.
// MODE 4 (L5, 512): outf = A @ Bt^T (f32).
template <int MODE>
__global__ __launch_bounds__(256, 2) void gemm_tree(
    const unsigned short* __restrict__ A, const unsigned short* __restrict__ Bt,
    const unsigned short* __restrict__ lin,
    unsigned short* __restrict__ O1, unsigned short* __restrict__ O2,
    float* __restrict__ outf) {
  __shared__ __align__(16) unsigned short ldsbuf[24576];  // 48 KB
  unsigned short* As = ldsbuf;
  unsigned short* Bs = ldsbuf + 16384;

  const int t = threadIdx.x;
  const int lane = t & 63, wid = t >> 6, wm = wid >> 1, wn = wid & 1;
  const int nb = (int)gridDim.x;
  const int swz = (blockIdx.x & 7) * (nb >> 3) + (blockIdx.x >> 3);  // XCD-bijective

  int bm, bn, z = 0, ks = 0;
  const unsigned short *Ap, *Btp;
  if (MODE == 0) {
    z = swz >> 7;
    const int rem = swz & 127;
    bm = rem >> 4; bn = rem & 15;
    Ap = A + (size_t)(2 * z) * SM;
    Btp = Bt + (size_t)z * SM;
  } else if (MODE == 1) {
    z = swz >> 8; ks = (swz >> 7) & 1;
    const int tile = swz & 127;
    bm = tile >> 4; bn = tile & 15;
    Ap = A + (size_t)(2 * z) * SM;
    Btp = Bt + (size_t)z * SM;
  } else if (MODE == 2 || MODE == 3) {
    ks = swz >> 7;
    const int tile = swz & 127;
    bm = tile >> 4; bn = tile & 15;
    Ap = A; Btp = Bt;
  } else {
    bm = swz >> 4; bn = swz & 15;
    Ap = A; Btp = Bt;
  }

  f32x4 acc[4][2];
#pragma unroll
  for (int m = 0; m < 4; ++m)
#pragma unroll
    for (int n = 0; n < 2; ++n) acc[m][n] = (f32x4)0.f;

  if (MODE == 0)      gemm_core<16>(Ap, Btp, bm * 128, bn * 64, 0,        t, As, Bs, acc);
  else if (MODE == 1) gemm_core<8>( Ap, Btp, bm * 128, bn * 64, ks * 512, t, As, Bs, acc);
  else if (MODE <= 3) gemm_core<4>( Ap, Btp, bm * 128, bn * 64, ks * 256, t, As, Bs, acc);
  else                gemm_core<16>(Ap, Btp, bm * 128, bn * 64, 0,        t, As, Bs, acc);

  // epilogue. C/D layout: col = lane&15, row = (lane>>4)*4 + reg [HW-verified]
#pragma unroll
  for (int m = 0; m < 4; ++m) {
    int Rb = bm * 128 + wm * 64 + m * 16 + ((lane >> 4) << 2);
#pragma unroll
    for (int n = 0; n < 2; ++n) {
      int C = bn * 64 + wn * 32 + n * 16 + (lane & 15);
      if (MODE == 0) {
        const unsigned short* aA = lin + (size_t)(2 * z) * SM;
        const unsigned short* aB = lin + (size_t)(2 * z + 1) * SM;
        unsigned short* pr = O1 + (size_t)z * SM;
        u16x4 tp;
#pragma unroll
        for (int r2 = 0; r2 < 4; ++r2) {
          size_t idx = (size_t)(Rb + r2) * FEAT + C;
          float v = acc[m][n][r2] + bf16_to_f32(aA[idx]) + bf16_to_f32(aB[idx]);
          unsigned short h = f32_to_bf16(v);
          pr[idx] = h; tp[r2] = h;
        }
        if (z & 1)
          *(u16x4*)(O2 + (size_t)(z >> 1) * SM + (size_t)C * FEAT + Rb) = tp;
      } else if (MODE >= 1 && MODE <= 3) {
        unsigned short* po = (MODE == 1) ? O1 + (size_t)(2 * z + ks) * SM
                                         : O1 + (size_t)ks * SM;
#pragma unroll
        for (int r2 = 0; r2 < 4; ++r2)
          po[(size_t)(Rb + r2) * FEAT + C] = f32_to_bf16(acc[m][n][r2]);
      } else {
#pragma unroll
        for (int r2 = 0; r2 < 4; ++r2)
          outf[(size_t)(Rb + r2) * FEAT + C] = acc[m][n][r2];
      }
    }
  }
}

// ---- reduce L2: P2r[z] = Pp[2z]+Pp[2z+1] + P1r[2z]+P1r[2z+1]; z==1 also transposed ----
__global__ void reduce_L2(const unsigned short* __restrict__ Pp,
                          const unsigned short* __restrict__ P1r,
                          unsigned short* __restrict__ P2r,
                          unsigned short* __restrict__ P2tR) {
  __shared__ unsigned short Ts[64][68];
  const int bid = blockIdx.x;
  const int t = threadIdx.x;
  const int z = bid >> 8, rem = bid & 255;
  const int k0 = (rem >> 4) * 64, n0 = (rem & 15) * 64;
  const unsigned short* p0 = Pp + (size_t)(2 * z) * SM;
  const unsigned short* p1 = Pp + (size_t)(2 * z + 1) * SM;
  const unsigned short* a0 = P1r + (size_t)(2 * z) * SM;
  const unsigned short* a1 = P1r + (size_t)(2 * z + 1) * SM;
  unsigned short* pr = P2r + (size_t)z * SM;
#pragma unroll
  for (int i2 = 0; i2 < 4; ++i2) {
    int fidx = i2 * 256 + t;
    int kl = fidx >> 4, nf = fidx & 15;
    size_t idx = (size_t)(k0 + kl) * FEAT + n0 + nf * 4;
    u16x4 v0 = *(const u16x4*)(p0 + idx);
    u16x4 v1 = *(const u16x4*)(p1 + idx);
    u16x4 q0 = *(const u16x4*)(a0 + idx);
    u16x4 q1 = *(const u16x4*)(a1 + idx);
    u16x4 o;
#pragma unroll
    for (int e = 0; e < 4; ++e)
      o[e] = f32_to_bf16(bf16_to_f32(v0[e]) + bf16_to_f32(v1[e]) +
                         bf16_to_f32(q0[e]) + bf16_to_f32(q1[e]));
    *(u16x4*)&Ts[kl][nf * 4] = o;
    *(u16x4*)(pr + idx) = o;
  }
  __syncthreads();
  if (z == 1) {
#pragma unroll
    for (int i2 = 0; i2 < 2; ++i2) {
      int cidx = t * 2 + i2;
      int nl = cidx >> 3, kc = (cidx & 7) * 8;
      u16x8 o;
#pragma unroll
      for (int r = 0; r < 8; ++r) o[r] = Ts[kc + r][nl];
      *(u16x8*)(P2tR + (size_t)(n0 + nl) * FEAT + k0 + kc) = o;
    }
  }
}

// ---- reduce L3: P3r = sum Pq[0..3] + P2r[0] + P2r[1] (rows only) ----
__global__ void reduce_L3(const unsigned short* __restrict__ Pq,
                          const unsigned short* __restrict__ P2r,
                          unsigned short* __restrict__ P3r) {
  const int i = blockIdx.x * blockDim.x + threadIdx.x;  // 65536 threads x u16x4... use grid-stride
  for (int c = i; c < SM / 4; c += 65536) {
    size_t idx = (size_t)c * 4;
    float s[4] = {0.f, 0.f, 0.f, 0.f};
#pragma unroll
    for (int p = 0; p < 4; ++p) {
      u16x4 v = *(const u16x4*)(Pq + (size_t)p * SM + idx);
#pragma unroll
      for (int e = 0; e < 4; ++e) s[e] += bf16_to_f32(v[e]);
    }
    u16x4 qL = *(const u16x4*)(P2r + idx);
    u16x4 qR = *(const u16x4*)(P2r + SM + idx);
    u16x4 o;
#pragma unroll
    for (int e = 0; e < 4; ++e)
      o[e] = f32_to_bf16(s[e] + bf16_to_f32(qL[e]) + bf16_to_f32(qR[e]));
    *(u16x4*)(P3r + idx) = o;
  }
}

// ---- reduce L4: St[n][k] = bf16( sum Pp[0..3][k][n] + Wb[n][k] )  (transposed) ----
__global__ void reduce_L4(const unsigned short* __restrict__ Pp,
                          const unsigned short* __restrict__ Wb,
                          unsigned short* __restrict__ St) {
  __shared__ float Tf[64][68];
  const int bid = blockIdx.x;
  const int t = threadIdx.x;
  const int k0 = (bid >> 4) * 64, n0 = (bid & 15) * 64;
#pragma unroll
  for (int i2 = 0; i2 < 4; ++i2) {
    int fidx = i2 * 256 + t;
    int kl = fidx >> 4, nf = fidx & 15;
    size_t idx = (size_t)(k0 + kl) * FEAT + n0 + nf * 4;
    float s[4] = {0.f, 0.f, 0.f, 0.f};
#pragma unroll
    for (int p = 0; p < 4; ++p) {
      u16x4 v = *(const u16x4*)(Pp + (size_t)p * SM + idx);
#pragma unroll
      for (int e = 0; e < 4; ++e) s[e] += bf16_to_f32(v[e]);
    }
#pragma unroll
    for (int e = 0; e < 4; ++e) Tf[kl][nf * 4 + e] = s[e];
  }
  __syncthreads();
#pragma unroll
  for (int i2 = 0; i2 < 2; ++i2) {
    int cidx = t * 2 + i2;
    int nl = cidx >> 3, kc = (cidx & 7) * 8;
    u16x8 o;
#pragma unroll
    for (int r = 0; r < 8; ++r) {
      float v = Tf[kc + r][nl] + bf16_to_f32(Wb[(size_t)(n0 + nl) * FEAT + k0 + kc + r]);
      o[r] = f32_to_bf16(v);
    }
    *(u16x8*)(St + (size_t)(n0 + nl) * FEAT + k0 + kc) = o;
  }
}

extern "C" void kernel_launch(void* const* d_in, const int* in_sizes, int n_in,
                              void* d_out, int out_size, void* d_ws, size_t ws_size,
                              hipStream_t stream) {
  const float* features = (const float*)d_in[0];
  const float* eps      = (const float*)d_in[1];
  const float* mean     = (const float*)d_in[2];
  const float* logvar   = (const float*)d_in[3];
  const float* task_mats= (const float*)d_in[4];
  const float* proj_w   = (const float*)d_in[5];
  float* out = (float*)d_out;

  // workspace layout (peak 72 MB):
  uint8_t* ws = (uint8_t*)d_ws;
  unsigned short* Dr   = (unsigned short*)(ws);                      //  0..16M
  unsigned short* Dt   = (unsigned short*)(ws + ((size_t)16 << 20)); // 16..24M (odd-packed)
  unsigned short* Xb   = (unsigned short*)(ws + ((size_t)24 << 20)); // 24..32M
  unsigned short* Wb   = (unsigned short*)(ws + ((size_t)32 << 20)); // 32..34M
  unsigned short* P1r  = (unsigned short*)(ws + ((size_t)34 << 20)); // 34..42M (4 slices)
  unsigned short* P1t  = (unsigned short*)(ws + ((size_t)42 << 20)); // 42..46M (odd-packed)
  unsigned short* Pp   = (unsigned short*)(ws + ((size_t)46 << 20)); // 46..54M (4 partial slots)
  unsigned short* P2r  = (unsigned short*)(ws + ((size_t)54 << 20)); // 54..58M (DL, DR rows)
  unsigned short* P2tR = (unsigned short*)(ws + ((size_t)58 << 20)); // 58..60M (DR^T)
  unsigned short* Pq   = (unsigned short*)(ws + ((size_t)60 << 20)); // 60..68M (4 partial slots)
  unsigned short* P3r  = (unsigned short*)(ws + ((size_t)68 << 20)); // 68..70M (Delta rows)
  unsigned short* St   = (unsigned short*)(ws + ((size_t)70 << 20)); // 70..72M (S^T)

  // prep: deltas + bf16 converts
  conv_all<<<2304, 256, 0, stream>>>(task_mats, features, proj_w, mean, eps, logvar,
                                     Dr, Dt, Xb, Wb);
  // L1: P1[z] = D2z + D2z+1 + D2z@D2z+1  (4 slices)
  gemm_tree<0><<<512, 256, 0, stream>>>(Dr, Dt, Dr, P1r, P1t, nullptr);
  // L2 split-K2 partials: P1_2z @ P1_2z+1 (z=0: DL, z=1: DR)
  gemm_tree<1><<<512, 256, 0, stream>>>(P1r, P1t, nullptr, Pp, nullptr, nullptr);
  // L2 reduce: P2r = partials + linears; DR also transposed
  reduce_L2<<<512, 256, 0, stream>>>(Pp, P1r, P2r, P2tR);
  // L3 split-K4 partials: DL @ DR
  gemm_tree<2><<<512, 256, 0, stream>>>(P2r, P2tR, nullptr, Pq, nullptr, nullptr);
  // L3 reduce: Delta = partials + DL + DR (rows)
  reduce_L3<<<256, 256, 0, stream>>>(Pq, P2r, P3r);
  // L4 split-K4 partials: Delta @ W^T  (Bt = Wb row-major)
  gemm_tree<3><<<512, 256, 0, stream>>>(P3r, Wb, nullptr, Pp, nullptr, nullptr);
  // L4 reduce: St = (W^T + Delta@W^T) transposed
  reduce_L4<<<256, 256, 0, stream>>>(Pp, Wb, St);
  // L5: out = x @ S (f32)
  gemm_tree<4><<<512, 256, 0, stream>>>(Xb, St, nullptr, nullptr, nullptr, out);
}

// Round 7
// 80.112 us; speedup vs baseline: 7.2327x; 1.0562x over previous
//
#include <hip/hip_runtime.h>
#include <stdint.h>

#define FEAT 1024
#define BATCH 4096
#define SM (FEAT * FEAT)

typedef float f32x4 __attribute__((ext_vector_type(4)));
typedef short bf16x8 __attribute__((ext_vector_type(8)));
typedef unsigned short u16x8 __attribute__((ext_vector_type(8)));
typedef unsigned short u16x4 __attribute__((ext_vector_type(4)));

__device__ inline unsigned short f32_to_bf16(float f) {
  union { float f; uint32_t u; } v; v.f = f;
  uint32_t u = v.u;
  uint32_t lsb = (u >> 16) & 1u;
  u += 0x7fffu + lsb;  // RNE
  return (unsigned short)(u >> 16);
}

__device__ inline float bf16_to_f32(unsigned short h) {
  union { uint32_t u; float f; } v; v.u = (uint32_t)h << 16; return v.f;
}

__device__ inline void gload_lds16(const void* g, void* l) {
  __builtin_amdgcn_global_load_lds(
      (__attribute__((address_space(1))) void*)(g),
      (__attribute__((address_space(3))) void*)(l),
      16, 0, 0);
}

// ---- fused prep: Dr[j]=bf16(c_j*M_j) (all j), Dt[j>>1]=transposed (odd j only),
// ---- Xb=bf16(features), Wb=bf16(proj_w). 2304 blocks.
__global__ void conv_all(const float* __restrict__ M, const float* __restrict__ feat,
                         const float* __restrict__ pw, const float* __restrict__ mean,
                         const float* __restrict__ eps, const float* __restrict__ logvar,
                         unsigned short* __restrict__ Dr, unsigned short* __restrict__ Dt,
                         unsigned short* __restrict__ Xb, unsigned short* __restrict__ Wb) {
  const int bid = blockIdx.x;
  const int t = threadIdx.x;
  if (bid < 2048) {
    __shared__ unsigned short Ts[64][68];
    const int j = bid >> 8, rem = bid & 255;
    const int n0 = (rem >> 4) * 64, k0 = (rem & 15) * 64;
    float lv = fminf(fmaxf(logvar[j], -8.f), 2.f);
    const float c = mean[j] + eps[j] * expf(0.5f * lv);
    const float* src = M + (size_t)j * SM;
    unsigned short* dr = Dr + (size_t)j * SM;
#pragma unroll
    for (int i2 = 0; i2 < 4; ++i2) {
      int fidx = i2 * 256 + t;
      int kl = fidx >> 4, nf = fidx & 15;
      float4 v = *(const float4*)(src + (size_t)(k0 + kl) * FEAT + n0 + nf * 4);
      u16x4 o;
      o[0] = f32_to_bf16(c * v.x); o[1] = f32_to_bf16(c * v.y);
      o[2] = f32_to_bf16(c * v.z); o[3] = f32_to_bf16(c * v.w);
      *(u16x4*)&Ts[kl][nf * 4] = o;
      *(u16x4*)(dr + (size_t)(k0 + kl) * FEAT + n0 + nf * 4) = o;
    }
    __syncthreads();
    if (j & 1) {
      unsigned short* dt = Dt + (size_t)(j >> 1) * SM;
#pragma unroll
      for (int i2 = 0; i2 < 2; ++i2) {
        int cidx = t * 2 + i2;
        int nl = cidx >> 3, kc = (cidx & 7) * 8;
        u16x8 o;
#pragma unroll
        for (int r = 0; r < 8; ++r) o[r] = Ts[kc + r][nl];
        *(u16x8*)(dt + (size_t)(n0 + nl) * FEAT + k0 + kc) = o;
      }
    }
  } else {
    for (int i = (bid - 2048) * 256 + t; i < 655360; i += 65536) {
      const float* in; unsigned short* o8; int ci;
      if (i < 524288) { in = feat; o8 = Xb; ci = i; }
      else            { in = pw;   o8 = Wb; ci = i - 524288; }
      const float4* p = (const float4*)in + (size_t)ci * 2;
      float4 a = p[0], b = p[1];
      u16x8 o;
      o[0] = f32_to_bf16(a.x); o[1] = f32_to_bf16(a.y);
      o[2] = f32_to_bf16(a.z); o[3] = f32_to_bf16(a.w);
      o[4] = f32_to_bf16(b.x); o[5] = f32_to_bf16(b.y);
      o[6] = f32_to_bf16(b.z); o[7] = f32_to_bf16(b.w);
      *((u16x8*)o8 + ci) = o;
    }
  }
}

// ---- 2-phase double-buffered 128x64-tile GEMM core (16 K-steps of 64) ----
// LDS: As = 2 x 8192 elems, Bs = 2 x 4096 elems (48 KB total).
// XOR-swizzled (colbyte ^= (row&7)<<4), pre-swizzled global source.
__device__ __forceinline__ void gemm_core128(
    const unsigned short* __restrict__ Ap, const unsigned short* __restrict__ Btp,
    int arow0, int bcol0, int t,
    unsigned short* As, unsigned short* Bs, f32x4 (&acc)[4][2]) {
  const int lane = t & 63;
  const int wid = t >> 6, wm = wid >> 1, wn = wid & 1;
  const int ar = t >> 3;
  const int acb = (((t & 7) ^ ((t >> 3) & 7)) << 4);
  const unsigned short* Abase = Ap + (size_t)(arow0 + ar) * FEAT + (acb >> 1);
  const unsigned short* Bbase = Btp + (size_t)(bcol0 + ar) * FEAT + (acb >> 1);
  unsigned short* AsP = As + t * 8;
  unsigned short* BsP = Bs + t * 8;

#pragma unroll
  for (int p = 0; p < 4; ++p) gload_lds16(Abase + (size_t)(p * 32) * FEAT, AsP + p * 2048);
#pragma unroll
  for (int p = 0; p < 2; ++p) gload_lds16(Bbase + (size_t)(p * 32) * FEAT, BsP + p * 2048);
  __syncthreads();

  for (int kt = 0; kt < 16; ++kt) {
    const int cur = kt & 1, nx = cur ^ 1;
    if (kt < 15) {
      const int ko = (kt + 1) * 64;
#pragma unroll
      for (int p = 0; p < 4; ++p)
        gload_lds16(Abase + (size_t)(p * 32) * FEAT + ko, AsP + nx * 8192 + p * 2048);
#pragma unroll
      for (int p = 0; p < 2; ++p)
        gload_lds16(Bbase + (size_t)(p * 32) * FEAT + ko, BsP + nx * 4096 + p * 2048);
    }
    const char* Asc = (const char*)(As + cur * 8192);
    const char* Bsc = (const char*)(Bs + cur * 4096);
#pragma unroll
    for (int kk = 0; kk < 2; ++kk) {
      bf16x8 a[4], b[2];
      const int cbase = kk * 64 + ((lane >> 4) << 4);
#pragma unroll
      for (int m = 0; m < 4; ++m) {
        int r = wm * 64 + m * 16 + (lane & 15);
        a[m] = *(const bf16x8*)(Asc + r * 128 + (cbase ^ ((r & 7) << 4)));
      }
#pragma unroll
      for (int n = 0; n < 2; ++n) {
        int r = wn * 32 + n * 16 + (lane & 15);
        b[n] = *(const bf16x8*)(Bsc + r * 128 + (cbase ^ ((r & 7) << 4)));
      }
#pragma unroll
      for (int m = 0; m < 4; ++m)
#pragma unroll
        for (int n = 0; n < 2; ++n)
          acc[m][n] = __builtin_amdgcn_mfma_f32_16x16x32_bf16(a[m], b[n], acc[m][n], 0, 0, 0);
    }
    __syncthreads();
  }
}

// MODE 0 (L1, 512): z=swz>>7; P1[z] = D2z + D2z+1 + D2z@D2z+1 -> O1+z*SM rows,
//        O2+(z>>1)*SM transposed if z odd.  lin = Dr.
// MODE 1 (L5, 512): outf = A @ Bt^T (f32).
template <int MODE>
__global__ __launch_bounds__(256, 2) void gemm128(
    const unsigned short* __restrict__ A, const unsigned short* __restrict__ Bt,
    const unsigned short* __restrict__ lin,
    unsigned short* __restrict__ O1, unsigned short* __restrict__ O2,
    float* __restrict__ outf) {
  __shared__ __align__(16) unsigned short ldsbuf[24576];  // 48 KB
  unsigned short* As = ldsbuf;
  unsigned short* Bs = ldsbuf + 16384;

  const int t = threadIdx.x;
  const int lane = t & 63, wid = t >> 6, wm = wid >> 1, wn = wid & 1;
  const int swz = (blockIdx.x & 7) * 64 + (blockIdx.x >> 3);  // 512 blocks, XCD-bijective

  int bm, bn, z = 0;
  const unsigned short *Ap, *Btp;
  if (MODE == 0) {
    z = swz >> 7;
    const int rem = swz & 127;
    bm = rem >> 4; bn = rem & 15;
    Ap = A + (size_t)(2 * z) * SM;
    Btp = Bt + (size_t)z * SM;
  } else {
    bm = swz >> 4; bn = swz & 15;
    Ap = A; Btp = Bt;
  }

  f32x4 acc[4][2];
#pragma unroll
  for (int m = 0; m < 4; ++m)
#pragma unroll
    for (int n = 0; n < 2; ++n) acc[m][n] = (f32x4)0.f;

  gemm_core128(Ap, Btp, bm * 128, bn * 64, t, As, Bs, acc);

  // epilogue. C/D layout: col = lane&15, row = (lane>>4)*4 + reg [HW-verified]
#pragma unroll
  for (int m = 0; m < 4; ++m) {
    int Rb = bm * 128 + wm * 64 + m * 16 + ((lane >> 4) << 2);
#pragma unroll
    for (int n = 0; n < 2; ++n) {
      int C = bn * 64 + wn * 32 + n * 16 + (lane & 15);
      if (MODE == 0) {
        const unsigned short* aA = lin + (size_t)(2 * z) * SM;
        const unsigned short* aB = lin + (size_t)(2 * z + 1) * SM;
        unsigned short* pr = O1 + (size_t)z * SM;
        u16x4 tp;
#pragma unroll
        for (int r2 = 0; r2 < 4; ++r2) {
          size_t idx = (size_t)(Rb + r2) * FEAT + C;
          float v = acc[m][n][r2] + bf16_to_f32(aA[idx]) + bf16_to_f32(aB[idx]);
          unsigned short h = f32_to_bf16(v);
          pr[idx] = h; tp[r2] = h;
        }
        if (z & 1)
          *(u16x4*)(O2 + (size_t)(z >> 1) * SM + (size_t)C * FEAT + Rb) = tp;
      } else {
#pragma unroll
        for (int r2 = 0; r2 < 4; ++r2)
          outf[(size_t)(Rb + r2) * FEAT + C] = acc[m][n][r2];
      }
    }
  }
}

// ---- 64x64-tile full-K GEMM, 32 KB LDS (high occupancy), fused linear epilogue ----
// MODE 0 (L2, 512 blocks): z=swz>>8; P2[z] = P1_2z + P1_2z+1 + P1_2z@P1_2z+1
//        A=P1r (row slices), Bt=P1t (odd-packed transposes), lin=P1r. Row-major out O+z*SM.
// MODE 1 (U/S, 256 blocks): O^T[C][k] = bf16( (A@Bt^T)[k][C] + lin[C][k] )
//        i.e. Y + lin^T, written transposed. lin is the [C][k]-layout operand (Wb or Ut).
template <int MODE>
__global__ __launch_bounds__(256, 2) void gemm64(
    const unsigned short* __restrict__ A, const unsigned short* __restrict__ Bt,
    const unsigned short* __restrict__ lin, unsigned short* __restrict__ O) {
  __shared__ __align__(16) unsigned short ldsbuf[16384];  // 32 KB: As 2x4096, Bs 2x4096
  unsigned short* As = ldsbuf;
  unsigned short* Bs = ldsbuf + 8192;

  const int t = threadIdx.x;
  const int lane = t & 63, wid = t >> 6, wm = wid >> 1, wn = wid & 1;
  const int nb = (int)gridDim.x;
  const int swz = (blockIdx.x & 7) * (nb >> 3) + (blockIdx.x >> 3);  // XCD-bijective

  int bm, bn, z = 0;
  const unsigned short *Ap, *Btp;
  if (MODE == 0) {
    z = swz >> 8;
    const int tile = swz & 255;
    bm = tile >> 4; bn = tile & 15;
    Ap = A + (size_t)(2 * z) * SM;
    Btp = Bt + (size_t)z * SM;
  } else {
    bm = swz >> 4; bn = swz & 15;
    Ap = A; Btp = Bt;
  }
  const int arow0 = bm * 64, bcol0 = bn * 64;

  f32x4 acc[2][2];
#pragma unroll
  for (int m = 0; m < 2; ++m)
#pragma unroll
    for (int n = 0; n < 2; ++n) acc[m][n] = (f32x4)0.f;

  const int ar = t >> 3;
  const int acb = (((t & 7) ^ ((t >> 3) & 7)) << 4);
  const unsigned short* Abase = Ap + (size_t)(arow0 + ar) * FEAT + (acb >> 1);
  const unsigned short* Bbase = Btp + (size_t)(bcol0 + ar) * FEAT + (acb >> 1);
  unsigned short* AsP = As + t * 8;
  unsigned short* BsP = Bs + t * 8;

#pragma unroll
  for (int p = 0; p < 2; ++p) gload_lds16(Abase + (size_t)(p * 32) * FEAT, AsP + p * 2048);
#pragma unroll
  for (int p = 0; p < 2; ++p) gload_lds16(Bbase + (size_t)(p * 32) * FEAT, BsP + p * 2048);
  __syncthreads();

  for (int kt = 0; kt < 16; ++kt) {
    const int cur = kt & 1, nx = cur ^ 1;
    if (kt < 15) {
      const int ko = (kt + 1) * 64;
#pragma unroll
      for (int p = 0; p < 2; ++p)
        gload_lds16(Abase + (size_t)(p * 32) * FEAT + ko, AsP + nx * 4096 + p * 2048);
#pragma unroll
      for (int p = 0; p < 2; ++p)
        gload_lds16(Bbase + (size_t)(p * 32) * FEAT + ko, BsP + nx * 4096 + p * 2048);
    }
    const char* Asc = (const char*)(As + cur * 4096);
    const char* Bsc = (const char*)(Bs + cur * 4096);
#pragma unroll
    for (int kk = 0; kk < 2; ++kk) {
      bf16x8 a[2], b[2];
      const int cbase = kk * 64 + ((lane >> 4) << 4);
#pragma unroll
      for (int m = 0; m < 2; ++m) {
        int r = wm * 32 + m * 16 + (lane & 15);
        a[m] = *(const bf16x8*)(Asc + r * 128 + (cbase ^ ((r & 7) << 4)));
      }
#pragma unroll
      for (int n = 0; n < 2; ++n) {
        int r = wn * 32 + n * 16 + (lane & 15);
        b[n] = *(const bf16x8*)(Bsc + r * 128 + (cbase ^ ((r & 7) << 4)));
      }
#pragma unroll
      for (int m = 0; m < 2; ++m)
#pragma unroll
        for (int n = 0; n < 2; ++n)
          acc[m][n] = __builtin_amdgcn_mfma_f32_16x16x32_bf16(a[m], b[n], acc[m][n], 0, 0, 0);
    }
    __syncthreads();
  }

  // epilogue
#pragma unroll
  for (int m = 0; m < 2; ++m) {
    int Rb = arow0 + wm * 32 + m * 16 + ((lane >> 4) << 2);
#pragma unroll
    for (int n = 0; n < 2; ++n) {
      int C = bcol0 + wn * 32 + n * 16 + (lane & 15);
      if (MODE == 0) {
        const unsigned short* aA = lin + (size_t)(2 * z) * SM;
        const unsigned short* aB = lin + (size_t)(2 * z + 1) * SM;
        unsigned short* po = O + (size_t)z * SM;
#pragma unroll
        for (int r2 = 0; r2 < 4; ++r2) {
          size_t idx = (size_t)(Rb + r2) * FEAT + C;
          float v = acc[m][n][r2] + bf16_to_f32(aA[idx]) + bf16_to_f32(aB[idx]);
          po[idx] = f32_to_bf16(v);
        }
      } else {
        u16x4 lv = *(const u16x4*)(lin + (size_t)C * FEAT + Rb);
        u16x4 o;
#pragma unroll
        for (int r2 = 0; r2 < 4; ++r2)
          o[r2] = f32_to_bf16(acc[m][n][r2] + bf16_to_f32(lv[r2]));
        *(u16x4*)(O + (size_t)C * FEAT + Rb) = o;  // transposed write
      }
    }
  }
}

extern "C" void kernel_launch(void* const* d_in, const int* in_sizes, int n_in,
                              void* d_out, int out_size, void* d_ws, size_t ws_size,
                              hipStream_t stream) {
  const float* features = (const float*)d_in[0];
  const float* eps      = (const float*)d_in[1];
  const float* mean     = (const float*)d_in[2];
  const float* logvar   = (const float*)d_in[3];
  const float* task_mats= (const float*)d_in[4];
  const float* proj_w   = (const float*)d_in[5];
  float* out = (float*)d_out;

  // workspace layout (peak 54 MB):
  uint8_t* ws = (uint8_t*)d_ws;
  unsigned short* Dr  = (unsigned short*)(ws);                      //  0..16M
  unsigned short* Dt  = (unsigned short*)(ws + ((size_t)16 << 20)); // 16..24M (odd-packed)
  unsigned short* Xb  = (unsigned short*)(ws + ((size_t)24 << 20)); // 24..32M
  unsigned short* Wb  = (unsigned short*)(ws + ((size_t)32 << 20)); // 32..34M
  unsigned short* P1r = (unsigned short*)(ws + ((size_t)34 << 20)); // 34..42M (4 slices)
  unsigned short* P1t = (unsigned short*)(ws + ((size_t)42 << 20)); // 42..46M (odd-packed)
  unsigned short* P2r = (unsigned short*)(ws + ((size_t)46 << 20)); // 46..50M (DL, DR rows)
  unsigned short* Ut  = (unsigned short*)(ws + ((size_t)50 << 20)); // 50..52M ((I+DR)W^T, transposed)
  unsigned short* St  = (unsigned short*)(ws + ((size_t)52 << 20)); // 52..54M (S, transposed)

  // prep: deltas + bf16 converts
  conv_all<<<2304, 256, 0, stream>>>(task_mats, features, proj_w, mean, eps, logvar,
                                     Dr, Dt, Xb, Wb);
  // L1: P1[z] = D2z + D2z+1 + D2z@D2z+1  (4 slices, 128x64 tiles)
  gemm128<0><<<512, 256, 0, stream>>>(Dr, Dt, Dr, P1r, P1t, nullptr);
  // L2: P2[z] = P1_2z + P1_2z+1 + P1_2z@P1_2z+1  (2 slices, 64x64 tiles, full-K)
  gemm64<0><<<512, 256, 0, stream>>>(P1r, P1t, P1r, P2r);
  // U = W^T + DR@W^T, written transposed: Ut[C][k]
  gemm64<1><<<256, 256, 0, stream>>>(P2r + SM, Wb, Wb, Ut);
  // S = U + DL@U, written transposed: St[C][k]
  gemm64<1><<<256, 256, 0, stream>>>(P2r, Ut, Ut, St);
  // L5: out = x @ S (f32, 128x64 tiles)
  gemm128<1><<<512, 256, 0, stream>>>(Xb, St, nullptr, nullptr, nullptr, out);
}